// Round 4
// baseline (442.419 us; speedup 1.0000x reference)
//
#include <hip/hip_runtime.h>

// Cross product along dim=1 of (16, 3, 1024, 1024) fp32 tensors.
// Layout (row-major): idx = ((b*3 + c)*1024 + h)*1024 + w.
// Component plane = 1024*1024 floats = P4 float4's; batch stride = 3 planes.
// Pure streaming: 604 MB total traffic, roofline ~96 us at 6.3 TB/s.
//
// vs. 441us baseline (still unmeasured — 4x infra failures):
//  - grid-stride loop (2048 blocks = 8192 waves, exactly fills 256CU*32),
//    2-deep unroll: 12 loads in flight per thread before any compute.
//  - nontemporal loads/stores: streams never re-read; keep them out of L2
//    (all 9 streams alias the same L2 sets at 4 MiB power-of-two strides).

typedef float vf4 __attribute__((ext_vector_type(4)));

#define P4 (1024 * 1024 / 4)   // float4 elements per component plane (262144, pow2)

__device__ __forceinline__ long plane_base(int i) {
    // i in [0, 16*P4): batch = i / P4, r = i % P4
    return (long)(i >> 18) * (3 * P4) + (i & (P4 - 1));
}

__global__ __launch_bounds__(256) void cross_kernel(
    const vf4* __restrict__ a,
    const vf4* __restrict__ b,
    vf4* __restrict__ out,
    int n4)   // total float4 positions = 16 * P4 = 4,194,304
{
    const int nth = gridDim.x * blockDim.x;
    int i = blockIdx.x * blockDim.x + threadIdx.x;

    // Pair-unrolled grid-stride loop: process i and i+nth together so all
    // 12 loads are outstanding before the first use.
    for (; i + nth < n4; i += 2 * nth) {
        const long p = plane_base(i);
        const long q = plane_base(i + nth);

        vf4 a0 = __builtin_nontemporal_load(a + p);
        vf4 a1 = __builtin_nontemporal_load(a + p + P4);
        vf4 a2 = __builtin_nontemporal_load(a + p + 2 * P4);
        vf4 b0 = __builtin_nontemporal_load(b + p);
        vf4 b1 = __builtin_nontemporal_load(b + p + P4);
        vf4 b2 = __builtin_nontemporal_load(b + p + 2 * P4);

        vf4 a3 = __builtin_nontemporal_load(a + q);
        vf4 a4 = __builtin_nontemporal_load(a + q + P4);
        vf4 a5 = __builtin_nontemporal_load(a + q + 2 * P4);
        vf4 b3 = __builtin_nontemporal_load(b + q);
        vf4 b4 = __builtin_nontemporal_load(b + q + P4);
        vf4 b5 = __builtin_nontemporal_load(b + q + 2 * P4);

        __builtin_nontemporal_store(a1 * b2 - a2 * b1, out + p);
        __builtin_nontemporal_store(a2 * b0 - a0 * b2, out + p + P4);
        __builtin_nontemporal_store(a0 * b1 - a1 * b0, out + p + 2 * P4);

        __builtin_nontemporal_store(a4 * b5 - a5 * b4, out + q);
        __builtin_nontemporal_store(a5 * b3 - a3 * b5, out + q + P4);
        __builtin_nontemporal_store(a3 * b4 - a4 * b3, out + q + 2 * P4);
    }

    // Tail: at most one leftover position per thread (stride-nth remainder).
    if (i < n4) {
        const long p = plane_base(i);
        vf4 a0 = __builtin_nontemporal_load(a + p);
        vf4 a1 = __builtin_nontemporal_load(a + p + P4);
        vf4 a2 = __builtin_nontemporal_load(a + p + 2 * P4);
        vf4 b0 = __builtin_nontemporal_load(b + p);
        vf4 b1 = __builtin_nontemporal_load(b + p + P4);
        vf4 b2 = __builtin_nontemporal_load(b + p + 2 * P4);
        __builtin_nontemporal_store(a1 * b2 - a2 * b1, out + p);
        __builtin_nontemporal_store(a2 * b0 - a0 * b2, out + p + P4);
        __builtin_nontemporal_store(a0 * b1 - a1 * b0, out + p + 2 * P4);
    }
}

extern "C" void kernel_launch(void* const* d_in, const int* in_sizes, int n_in,
                              void* d_out, int out_size, void* d_ws, size_t ws_size,
                              hipStream_t stream) {
    const vf4* a = (const vf4*)d_in[0];
    const vf4* b = (const vf4*)d_in[1];
    vf4* out = (vf4*)d_out;

    // out_size = 16*3*1024*1024 floats; positions (b,h,w) = out_size/3; /4 for float4
    int n4 = out_size / 3 / 4;   // 4,194,304
    int block = 256;
    // 8 positions per thread -> 2048 blocks (8 blocks/CU), 4 unrolled pair-iters.
    int grid = (n4 + block * 8 - 1) / (block * 8);
    cross_kernel<<<grid, block, 0, stream>>>(a, b, out, n4);
}